// Round 9
// baseline (103.153 us; speedup 1.0000x reference)
//
#include <hip/hip_runtime.h>
#include <stdint.h>

// x: (16, 3, 512, 512) fp32 -> magnitude (b,h,w) ++ angle (b,h,w), fp32.
// Sobel (kornia normalized, cross-correlation, 'edge' padding = clamp).
//
// Rolling-band pipeline: block owns a 32-row band, 8 iterations x 4 rows.
// Ring of 3 LDS tile slots; tile I(j) = 3ch x 4 input rows starting at
// band_start-1+4j. Iteration i: issue stage I(i+2) (fire-and-forget
// global_load_lds), counted s_waitcnt vmcnt(6) (waits I(i+1), keeps the
// prefetch in flight), s_barrier, compute O(i) rows from I(i),I(i+1).
// Halo columns via __shfl from neighbor lanes (no conflicted LDS scalars).

constexpr int Hc = 512;
constexpr int Wc = 512;
constexpr int Cc = 3;
constexpr int RT = 4;               // rows per iteration == waves per block
constexpr int ITERS = 8;            // band = 32 output rows
constexpr int SLOTS = 3;            // ring slots
constexpr int TILE_F = Cc * RT * Wc;  // 6144 floats per slot

__global__ __launch_bounds__(256, 1) void sobel_mag_angle_kernel(
    const float* __restrict__ x, float* __restrict__ out, int B) {
    __shared__ float lds[SLOTS * TILE_F];          // 73728 B

    int bid = blockIdx.x;
    int b = bid >> 4;                              // 16 bands per image
    int bstart = (bid & 15) << 5;                  // band start row

    int t = threadIdx.x;
    int wave = t >> 6;                             // 0..3
    int lane = t & 63;
    int w0 = lane << 3;                            // 8 px per lane
    bool l0 = (lane == 0), l63 = (lane == 63);

    const float* xb = x + (size_t)b * (Cc * Hc * Wc);

    // Stage tile j (3ch x 4 rows at bstart-1+4j, row-clamped) into slot j%3.
    // 24 x 1KB global_load_lds per tile; 6 per wave. Fire-and-forget.
    auto stage = [&](int j) {
        int slot = j % SLOTS;
#pragma unroll
        for (int s2 = 0; s2 < 6; ++s2) {
            int s = wave * 6 + s2;                 // 0..23
            int c = s >> 3;
            int k = (s >> 1) & 3;
            int half = s & 1;
            int g = bstart - 1 + (j << 2) + k;     // vertical clamp ('edge')
            g = g < 0 ? 0 : (g > Hc - 1 ? Hc - 1 : g);
            const float* gp = xb + ((size_t)c * Hc + g) * Wc + half * 256 + lane * 4;
            float* lp = &lds[slot * TILE_F + (c * RT + k) * Wc + half * 256];
            __builtin_amdgcn_global_load_lds(
                (const __attribute__((address_space(1))) void*)gp,
                (__attribute__((address_space(3))) void*)lp, 16, 0, 0);
        }
    };

    stage(0);
    stage(1);

    size_t npix = (size_t)B * (Hc * Wc);

    for (int i = 0; i < ITERS; ++i) {
        stage(i + 2);  // i=7 stages a clamped dummy tile into the dead slot — keeps vmcnt accounting uniform
        asm volatile("s_waitcnt vmcnt(6)" ::: "memory");  // waits I(i+1); this iter's 6 stay in flight
        __builtin_amdgcn_s_barrier();
        __builtin_amdgcn_sched_barrier(0);

        int si = i % SLOTS, si1 = (i + 1) % SLOTS;
        // wave handles output row g = bstart + 4i + wave; inputs g-1,g,g+1.
        float bm[8], bgx[8], bgy[8];
#pragma unroll
        for (int c = 0; c < Cc; ++c) {
            float row[3][10];                      // cols w0-1 .. w0+8
#pragma unroll
            for (int d = 0; d < 3; ++d) {
                int idx = wave + d;                // offset within I(i)/I(i+1)
                int slot = idx < 4 ? si : si1;
                int k = idx < 4 ? idx : idx - 4;
                const float* lrow = &lds[slot * TILE_F + (c * RT + k) * Wc];
                float4 A  = *(const float4*)(lrow + w0);
                float4 Bv = *(const float4*)(lrow + w0 + 4);
                float lh = __shfl_up(Bv.w, 1);  lh = l0 ? A.x : lh;   // col w0-1 (clamped)
                float rh = __shfl_down(A.x, 1); rh = l63 ? Bv.w : rh; // col w0+8 (clamped)
                row[d][0] = lh;
                row[d][1] = A.x;  row[d][2] = A.y;  row[d][3] = A.z;  row[d][4] = A.w;
                row[d][5] = Bv.x; row[d][6] = Bv.y; row[d][7] = Bv.z; row[d][8] = Bv.w;
                row[d][9] = rh;
            }
#pragma unroll
            for (int ii = 0; ii < 8; ++ii) {
                float t0 = row[0][ii + 2] - row[0][ii];
                float t1 = row[1][ii + 2] - row[1][ii];
                float t2 = row[2][ii + 2] - row[2][ii];
                float gx = 0.125f * (t0 + t2) + 0.25f * t1;
                float u0 = row[2][ii]     - row[0][ii];
                float u1 = row[2][ii + 1] - row[0][ii + 1];
                float u2 = row[2][ii + 2] - row[0][ii + 2];
                float gy = 0.125f * (u0 + u2) + 0.25f * u1;
                float m = __builtin_amdgcn_sqrtf(gx * gx + gy * gy + 1e-9f);
                if (c == 0) {
                    bm[ii] = m; bgx[ii] = gx; bgy[ii] = gy;
                } else {
                    bool gt = m > bm[ii];          // strict > = first-occurrence argmax
                    bm[ii]  = gt ? m  : bm[ii];
                    bgx[ii] = gt ? gx : bgx[ii];
                    bgy[ii] = gt ? gy : bgy[ii];
                }
            }
        }

        float mo[8], ao[8];
#pragma unroll
        for (int ii = 0; ii < 8; ++ii) {
            mo[ii] = bm[ii];
            float yt = (bgy[ii] == 0.0f) ? 1e-9f : bgy[ii];
            float a = bgx[ii] * __builtin_amdgcn_rcpf(yt);  // clipped to ±10 anyway
            ao[ii] = fminf(fmaxf(a, -10.0f), 10.0f);
        }

        int g = bstart + (i << 2) + wave;
        size_t obase = ((size_t)b * Hc + g) * Wc;
        float* po = out + obase;
        *(float4*)(po + w0)            = make_float4(mo[0], mo[1], mo[2], mo[3]);
        *(float4*)(po + w0 + 4)        = make_float4(mo[4], mo[5], mo[6], mo[7]);
        *(float4*)(po + npix + w0)     = make_float4(ao[0], ao[1], ao[2], ao[3]);
        *(float4*)(po + npix + w0 + 4) = make_float4(ao[4], ao[5], ao[6], ao[7]);

        __builtin_amdgcn_sched_barrier(0);
        __builtin_amdgcn_s_barrier();   // protect slot i%3 before next iter's overwrite
    }
}

extern "C" void kernel_launch(void* const* d_in, const int* in_sizes, int n_in,
                              void* d_out, int out_size, void* d_ws, size_t ws_size,
                              hipStream_t stream) {
    const float* x = (const float*)d_in[0];
    float* out = (float*)d_out;
    int B = in_sizes[0] / (Cc * Hc * Wc);        // 16
    int blocks = B * (Hc / (RT * ITERS));        // 256 = exactly 1 per CU
    sobel_mag_angle_kernel<<<blocks, 256, 0, stream>>>(x, out, B);
}

// Round 10
// 99.879 us; speedup vs baseline: 1.0328x; 1.0328x over previous
//
#include <hip/hip_runtime.h>
#include <stdint.h>

// x: (16, 3, 512, 512) fp32 -> magnitude (b,h,w) ++ angle (b,h,w), fp32.
// Sobel (kornia normalized, cross-correlation, 'edge' padding = clamp).
//
// R10: rolling-band, self-contained tiles, counted-vmcnt depth-1 prefetch.
//  - block = 512 thr (8 waves, 2/SIMD), owns a 32-row band, 4 iters x 8 rows
//  - tile I(j) = 3ch x 10 rows (rows bstart-1+8j .. +8) = 60 KB, ring of 2
//  - iter i: issue stage(i+1) fire-and-forget, s_waitcnt vmcnt(8) (waits only
//    tile i; prefetch stays in flight through compute), raw s_barrier
//    (NOT __syncthreads -- that drains vmcnt(0) and kills the pipeline)
//  - compute: wave r -> output row, 8 px/lane, shuffle halos (R9-verified)

constexpr int Hc = 512;
constexpr int Wc = 512;
constexpr int Cc = 3;
constexpr int TROWS = 10;                 // tile rows (8 output + 2 halo)
constexpr int TILE_F = Cc * TROWS * Wc;   // 15360 floats = 60 KB
constexpr int ITERS = 4;                  // band = 32 rows

__global__ __launch_bounds__(512, 2) void sobel_mag_angle_kernel(
    const float* __restrict__ x, float* __restrict__ out, int B) {
    __shared__ float lds[2 * TILE_F];     // 120 KB, 1 block/CU

    int bid = blockIdx.x;
    int b = bid >> 4;                     // 16 bands per image
    int bstart = (bid & 15) << 5;         // band start row

    int t = threadIdx.x;
    int wave = t >> 6;                    // 0..7 (wave-uniform)
    int lane = t & 63;
    int w0 = lane << 3;                   // 8 px per lane
    bool l0 = (lane == 0), l63 = (lane == 63);

    const float* xb = x + (size_t)b * (Cc * Hc * Wc);

    // Stage tile j into slot j&1: 60 half-row (1 KB) loads + 4 padded dups
    // so every wave issues exactly 8 (uniform vmcnt accounting).
    auto stage = [&](int j) {
        int slot = j & 1;
        int g0 = bstart - 1 + (j << 3);
#pragma unroll
        for (int s2 = 0; s2 < 8; ++s2) {
            int s = wave * 8 + s2;
            if (s > 59) s = 59;                      // dup, harmless
            int c = s / 20;
            int rem = s - c * 20;
            int k = rem >> 1;
            int half = rem & 1;
            int g = g0 + k;                           // vertical clamp ('edge')
            g = g < 0 ? 0 : (g > Hc - 1 ? Hc - 1 : g);
            const float* gp = xb + ((size_t)c * Hc + g) * Wc + half * 256 + lane * 4;
            float* lp = &lds[slot * TILE_F + (c * TROWS + k) * Wc + half * 256];
            __builtin_amdgcn_global_load_lds(
                (const __attribute__((address_space(1))) void*)gp,
                (__attribute__((address_space(3))) void*)lp, 16, 0, 0);
        }
    };

    stage(0);

    size_t npix = (size_t)B * (Hc * Wc);

#pragma unroll
    for (int i = 0; i < ITERS; ++i) {
        if (i < ITERS - 1) {
            stage(i + 1);                              // depth-1 prefetch
            asm volatile("s_waitcnt vmcnt(8)" ::: "memory");  // tile i landed
        } else {
            asm volatile("s_waitcnt vmcnt(0)" ::: "memory");  // drain last tile
        }
        __builtin_amdgcn_s_barrier();
        __builtin_amdgcn_sched_barrier(0);

        int slot = i & 1;
        // wave handles output row g = bstart + 8i + wave;
        // tile rows wave, wave+1, wave+2 == global rows g-1, g, g+1.
        float bm[8], bgx[8], bgy[8];
#pragma unroll
        for (int c = 0; c < Cc; ++c) {
            float row[3][10];                          // cols w0-1 .. w0+8
#pragma unroll
            for (int d = 0; d < 3; ++d) {
                const float* lrow = &lds[slot * TILE_F + (c * TROWS + wave + d) * Wc];
                float4 A  = *(const float4*)(lrow + w0);
                float4 Bv = *(const float4*)(lrow + w0 + 4);
                float lh = __shfl_up(Bv.w, 1);  lh = l0 ? A.x : lh;   // col w0-1
                float rh = __shfl_down(A.x, 1); rh = l63 ? Bv.w : rh; // col w0+8
                row[d][0] = lh;
                row[d][1] = A.x;  row[d][2] = A.y;  row[d][3] = A.z;  row[d][4] = A.w;
                row[d][5] = Bv.x; row[d][6] = Bv.y; row[d][7] = Bv.z; row[d][8] = Bv.w;
                row[d][9] = rh;
            }
#pragma unroll
            for (int ii = 0; ii < 8; ++ii) {
                float t0 = row[0][ii + 2] - row[0][ii];
                float t1 = row[1][ii + 2] - row[1][ii];
                float t2 = row[2][ii + 2] - row[2][ii];
                float gx = 0.125f * (t0 + t2) + 0.25f * t1;
                float u0 = row[2][ii]     - row[0][ii];
                float u1 = row[2][ii + 1] - row[0][ii + 1];
                float u2 = row[2][ii + 2] - row[0][ii + 2];
                float gy = 0.125f * (u0 + u2) + 0.25f * u1;
                float m = __builtin_amdgcn_sqrtf(gx * gx + gy * gy + 1e-9f);
                if (c == 0) {
                    bm[ii] = m; bgx[ii] = gx; bgy[ii] = gy;
                } else {
                    bool gt = m > bm[ii];              // strict > = first-occurrence
                    bm[ii]  = gt ? m  : bm[ii];
                    bgx[ii] = gt ? gx : bgx[ii];
                    bgy[ii] = gt ? gy : bgy[ii];
                }
            }
        }

        float mo[8], ao[8];
#pragma unroll
        for (int ii = 0; ii < 8; ++ii) {
            mo[ii] = bm[ii];
            float yt = (bgy[ii] == 0.0f) ? 1e-9f : bgy[ii];
            float a = bgx[ii] * __builtin_amdgcn_rcpf(yt);  // clipped to ±10 anyway
            ao[ii] = fminf(fmaxf(a, -10.0f), 10.0f);
        }

        int g = bstart + (i << 3) + wave;
        size_t obase = ((size_t)b * Hc + g) * Wc;
        float* po = out + obase;
        *(float4*)(po + w0)            = make_float4(mo[0], mo[1], mo[2], mo[3]);
        *(float4*)(po + w0 + 4)        = make_float4(mo[4], mo[5], mo[6], mo[7]);
        *(float4*)(po + npix + w0)     = make_float4(ao[0], ao[1], ao[2], ao[3]);
        *(float4*)(po + npix + w0 + 4) = make_float4(ao[4], ao[5], ao[6], ao[7]);

        __builtin_amdgcn_sched_barrier(0);
        __builtin_amdgcn_s_barrier();   // protect slot before next stage overwrites
    }
}

extern "C" void kernel_launch(void* const* d_in, const int* in_sizes, int n_in,
                              void* d_out, int out_size, void* d_ws, size_t ws_size,
                              hipStream_t stream) {
    const float* x = (const float*)d_in[0];
    float* out = (float*)d_out;
    int B = in_sizes[0] / (Cc * Hc * Wc);      // 16
    int blocks = B * (Hc / 32);                // 256 = one per CU
    sobel_mag_angle_kernel<<<blocks, 512, 0, stream>>>(x, out, B);
}

// Round 11
// 98.352 us; speedup vs baseline: 1.0488x; 1.0155x over previous
//
#include <hip/hip_runtime.h>
#include <stdint.h>

// x: (16, 3, 512, 512) fp32 -> magnitude (b,h,w) ++ angle (b,h,w), fp32.
// Sobel (kornia normalized, cross-correlation, 'edge' padding = clamp).
//
// R11 = R10 skeleton + conflict-free LDS reads.
//  R10 lesson: ds_read_b128 at 32B lane stride = 16-way bank conflict
//  (~20 us/CU of LDS serialization -- the real limiter, not HBM).
//  Fix: lane covers two contiguous 4-px chunks (A: px 4l.., B: px 256+4l..)
//  -> all b128 reads contiguous (16B lane stride, conflict-free);
//  halo px via 4 __shfl (ds_bpermute), lane wrap gives cross-chunk values.

constexpr int Hc = 512;
constexpr int Wc = 512;
constexpr int Cc = 3;
constexpr int TROWS = 10;                 // tile rows (8 output + 2 halo)
constexpr int TILE_F = Cc * TROWS * Wc;   // 15360 floats = 60 KB
constexpr int ITERS = 4;                  // band = 32 rows

__global__ __launch_bounds__(512, 2) void sobel_mag_angle_kernel(
    const float* __restrict__ x, float* __restrict__ out, int B) {
    __shared__ float lds[2 * TILE_F];     // 120 KB, 1 block/CU

    int bid = blockIdx.x;
    int b = bid >> 4;                     // 16 bands per image
    int bstart = (bid & 15) << 5;         // band start row

    int t = threadIdx.x;
    int wave = t >> 6;                    // 0..7 (wave-uniform)
    int lane = t & 63;
    bool l0 = (lane == 0), l63 = (lane == 63);

    const float* xb = x + (size_t)b * (Cc * Hc * Wc);

    // Stage tile j into slot j&1: 60 half-row (1 KB) loads + 4 dups so every
    // wave issues exactly 8 (uniform vmcnt accounting). Fire-and-forget.
    auto stage = [&](int j) {
        int slot = j & 1;
        int g0 = bstart - 1 + (j << 3);
#pragma unroll
        for (int s2 = 0; s2 < 8; ++s2) {
            int s = wave * 8 + s2;
            if (s > 59) s = 59;                      // dup, harmless
            int c = s / 20;
            int rem = s - c * 20;
            int k = rem >> 1;
            int half = rem & 1;
            int g = g0 + k;                           // vertical clamp ('edge')
            g = g < 0 ? 0 : (g > Hc - 1 ? Hc - 1 : g);
            const float* gp = xb + ((size_t)c * Hc + g) * Wc + half * 256 + lane * 4;
            float* lp = &lds[slot * TILE_F + (c * TROWS + k) * Wc + half * 256];
            __builtin_amdgcn_global_load_lds(
                (const __attribute__((address_space(1))) void*)gp,
                (__attribute__((address_space(3))) void*)lp, 16, 0, 0);
        }
    };

    stage(0);

    size_t npix = (size_t)B * (Hc * Wc);

#pragma unroll
    for (int i = 0; i < ITERS; ++i) {
        if (i < ITERS - 1) {
            stage(i + 1);                              // depth-1 prefetch
            asm volatile("s_waitcnt vmcnt(8)" ::: "memory");  // tile i landed
        } else {
            asm volatile("s_waitcnt vmcnt(0)" ::: "memory");  // drain last tile
        }
        __builtin_amdgcn_s_barrier();
        __builtin_amdgcn_sched_barrier(0);

        int slot = i & 1;
        // wave -> output row g = bstart + 8i + wave; tile rows wave..wave+2.
        float bmA[4], bgxA[4], bgyA[4], bmB[4], bgxB[4], bgyB[4];
#pragma unroll
        for (int c = 0; c < Cc; ++c) {
            float colA[3][6], colB[3][6];   // cols: halo, 4 px, halo
#pragma unroll
            for (int d = 0; d < 3; ++d) {
                const float* lrow = &lds[slot * TILE_F + (c * TROWS + wave + d) * Wc];
                float4 va = *(const float4*)(lrow + 4 * lane);        // px 4l..
                float4 vb = *(const float4*)(lrow + 256 + 4 * lane);  // px 256+4l..
                float pwa = __shfl(va.w, lane - 1);  // px 4l-1  (lane0 -> px255)
                float nxa = __shfl(va.x, lane + 1);  // px 4l+4  (lane63 -> px0, unused)
                float pwb = __shfl(vb.w, lane - 1);  // px 256+4l-1 (lane0 -> px511, unused)
                float nxb = __shfl(vb.x, lane + 1);  // px 256+4l+4 (lane63 -> px256)
                colA[d][0] = l0 ? va.x : pwa;        // clamp px-1 -> px0
                colA[d][1] = va.x; colA[d][2] = va.y; colA[d][3] = va.z; colA[d][4] = va.w;
                colA[d][5] = l63 ? nxb : nxa;        // px 256 via wrap
                colB[d][0] = l0 ? pwa : pwb;         // px 255 via wrap
                colB[d][1] = vb.x; colB[d][2] = vb.y; colB[d][3] = vb.z; colB[d][4] = vb.w;
                colB[d][5] = l63 ? vb.w : nxb;       // clamp px512 -> px511
            }
#pragma unroll
            for (int ii = 0; ii < 4; ++ii) {
                {   // chunk A
                    float t0 = colA[0][ii + 2] - colA[0][ii];
                    float t1 = colA[1][ii + 2] - colA[1][ii];
                    float t2 = colA[2][ii + 2] - colA[2][ii];
                    float gx = 0.125f * (t0 + t2) + 0.25f * t1;
                    float u0 = colA[2][ii]     - colA[0][ii];
                    float u1 = colA[2][ii + 1] - colA[0][ii + 1];
                    float u2 = colA[2][ii + 2] - colA[0][ii + 2];
                    float gy = 0.125f * (u0 + u2) + 0.25f * u1;
                    float m = __builtin_amdgcn_sqrtf(gx * gx + gy * gy + 1e-9f);
                    if (c == 0) { bmA[ii] = m; bgxA[ii] = gx; bgyA[ii] = gy; }
                    else {
                        bool gt = m > bmA[ii];       // strict > = first-occurrence
                        bmA[ii]  = gt ? m  : bmA[ii];
                        bgxA[ii] = gt ? gx : bgxA[ii];
                        bgyA[ii] = gt ? gy : bgyA[ii];
                    }
                }
                {   // chunk B
                    float t0 = colB[0][ii + 2] - colB[0][ii];
                    float t1 = colB[1][ii + 2] - colB[1][ii];
                    float t2 = colB[2][ii + 2] - colB[2][ii];
                    float gx = 0.125f * (t0 + t2) + 0.25f * t1;
                    float u0 = colB[2][ii]     - colB[0][ii];
                    float u1 = colB[2][ii + 1] - colB[0][ii + 1];
                    float u2 = colB[2][ii + 2] - colB[0][ii + 2];
                    float gy = 0.125f * (u0 + u2) + 0.25f * u1;
                    float m = __builtin_amdgcn_sqrtf(gx * gx + gy * gy + 1e-9f);
                    if (c == 0) { bmB[ii] = m; bgxB[ii] = gx; bgyB[ii] = gy; }
                    else {
                        bool gt = m > bmB[ii];
                        bmB[ii]  = gt ? m  : bmB[ii];
                        bgxB[ii] = gt ? gx : bgxB[ii];
                        bgyB[ii] = gt ? gy : bgyB[ii];
                    }
                }
            }
        }

        float moA[4], aoA[4], moB[4], aoB[4];
#pragma unroll
        for (int ii = 0; ii < 4; ++ii) {
            moA[ii] = bmA[ii];
            float yta = (bgyA[ii] == 0.0f) ? 1e-9f : bgyA[ii];
            float aa = bgxA[ii] * __builtin_amdgcn_rcpf(yta);
            aoA[ii] = fminf(fmaxf(aa, -10.0f), 10.0f);
            moB[ii] = bmB[ii];
            float ytb = (bgyB[ii] == 0.0f) ? 1e-9f : bgyB[ii];
            float ab = bgxB[ii] * __builtin_amdgcn_rcpf(ytb);
            aoB[ii] = fminf(fmaxf(ab, -10.0f), 10.0f);
        }

        int g = bstart + (i << 3) + wave;
        size_t obase = ((size_t)b * Hc + g) * Wc;
        float* po = out + obase;
        *(float4*)(po + 4 * lane)              = make_float4(moA[0], moA[1], moA[2], moA[3]);
        *(float4*)(po + 256 + 4 * lane)        = make_float4(moB[0], moB[1], moB[2], moB[3]);
        *(float4*)(po + npix + 4 * lane)       = make_float4(aoA[0], aoA[1], aoA[2], aoA[3]);
        *(float4*)(po + npix + 256 + 4 * lane) = make_float4(aoB[0], aoB[1], aoB[2], aoB[3]);

        __builtin_amdgcn_sched_barrier(0);
        __builtin_amdgcn_s_barrier();   // protect slot before next stage overwrites
    }
}

extern "C" void kernel_launch(void* const* d_in, const int* in_sizes, int n_in,
                              void* d_out, int out_size, void* d_ws, size_t ws_size,
                              hipStream_t stream) {
    const float* x = (const float*)d_in[0];
    float* out = (float*)d_out;
    int B = in_sizes[0] / (Cc * Hc * Wc);      // 16
    int blocks = B * (Hc / 32);                // 256 = one per CU
    sobel_mag_angle_kernel<<<blocks, 512, 0, stream>>>(x, out, B);
}